// Round 13
// baseline (390.189 us; speedup 1.0000x reference)
//
#include <hip/hip_runtime.h>
#include <math.h>

// ComplexEMA: B=2, D=1024, N=16, L=4096.
// y[b,d,l] = Re( sum_n gp[d,n] * h[d,n,l] ) + omega[d]*x[b,d,l]
//   h[n,l] = q[n]*h[n,l-1] + x[l]
// v5: v3's coalesced LDS staging + 2 waves/channel (block=128, 32 elems/lane
//     -> 4096 waves = 4/SIMD target occupancy). In-wave 6-step KS with
//     multiplier ladder in LDS (keeps VGPR low); wave1 folds wave0's TOTAL
//     prefix T with exact per-lane power q^{32*lam} (square-and-multiply from
//     ladder bits) -- fixes v4's approximate cross-wave carry. Pass C via LDS,
//     coalesced in/out. v4 lesson: per-lane-contiguous global access = 11x
//     HBM over-fetch; never again.

#define Bq 2
#define Dq 1024
#define Nq 16
#define Lq 4096
#define CH 32
#define STR 36   // chunk stride in floats: 144B, 16B-aligned

__global__ __launch_bounds__(128, 4) void cema_kernel(
    const float* __restrict__ x,
    const float* __restrict__ alpha,
    const float* __restrict__ delta,
    const float* __restrict__ theta,
    const float* __restrict__ gmr,
    const float* __restrict__ gmi,
    const float* __restrict__ omg,
    float* __restrict__ out)
{
    __shared__ float xs[128 * STR];        // 18432 B
    __shared__ float cqr[Nq], cqi[Nq], cgr[Nq], cgi[Nq];
    __shared__ float Ms[6][2][Nq];         // (q^32)^(2^k), k=0..5
    __shared__ float Tbuf[2][Nq];          // wave0 total prefix (lane 63)

    const int bd  = blockIdx.x;            // 0..2047
    const int d   = bd & (Dq - 1);
    const int t   = threadIdx.x;           // 0..127
    const int w   = t >> 6;                // wave id
    const int lam = t & 63;                // lane in wave

    const float* xp = x   + (size_t)bd * Lq;
    float*       yp = out + (size_t)bd * Lq;

    // ---- stage x into LDS, coalesced float4 ----
    #pragma unroll
    for (int i = 0; i < 8; ++i) {
        int e = i * 512 + t * 4;
        float4 v = *reinterpret_cast<const float4*>(xp + e);
        *reinterpret_cast<float4*>(&xs[(e >> 5) * STR + (e & 31)]) = v;
    }

    // ---- coefficients + q^32 ladder (threads 0..15) ----
    if (t < Nq) {
        const int n = t;
        float th  = theta[d];
        float f   = 1.f / (1.f + expf(-th));
        float phi = (float)(n + 1) * f * (float)(2.0 * M_PI / 16.0);
        float a   = 1.f / (1.f + expf(-alpha[d * Nq + n]));
        float dd  = 1.f / (1.f + expf(-delta[d * Nq + n]));
        float radius = fminf(1.f - a * dd, 1.f);
        float s, c;
        sincosf(phi, &s, &c);
        float qrv = radius * c, qiv = radius * s;
        cqr[n] = qrv; cqi[n] = qiv;
        cgr[n] = gmr[d * Nq + n] * 0.25f * a;   // scale = 1/sqrt(16)
        cgi[n] = gmi[d * Nq + n] * 0.25f * a;
        float mr = qrv, mi = qiv;               // q -> q^32 (5 squarings)
        #pragma unroll
        for (int k = 0; k < 5; ++k) { float t2 = mr*mr - mi*mi; mi = 2.f*mr*mi; mr = t2; }
        #pragma unroll
        for (int k = 0; k < 6; ++k) {           // ladder (q^32)^(2^k)
            Ms[k][0][n] = mr; Ms[k][1][n] = mi;
            float t2 = mr*mr - mi*mi; mi = 2.f*mr*mi; mr = t2;
        }
    }
    __syncthreads();

    float qrr[Nq], qii[Nq], hr[Nq], hi_[Nq];
    #pragma unroll
    for (int n = 0; n < Nq; ++n) {
        qrr[n] = cqr[n]; qii[n] = cqi[n];
        hr[n] = 0.f; hi_[n] = 0.f;
    }

    // ---- pass A: local scan of own 32-elem chunk from LDS ----
    const float4* xc4 = reinterpret_cast<const float4*>(&xs[t * STR]);
    for (int j = 0; j < 8; ++j) {
        float4 cur = xc4[j];
        #pragma unroll
        for (int u = 0; u < 4; ++u) {
            float xe = (u == 0) ? cur.x : (u == 1) ? cur.y : (u == 2) ? cur.z : cur.w;
            #pragma unroll
            for (int n = 0; n < Nq; ++n) {
                float nr = fmaf(qrr[n], hr[n], fmaf(-qii[n], hi_[n], xe));
                float ni = fmaf(qrr[n], hi_[n], qii[n] * hr[n]);
                hr[n] = nr; hi_[n] = ni;
            }
        }
    }

    // ---- in-wave KS scan (6 steps) + per-lane power pw = (q^32)^lam ----
    float pwr[Nq], pwi[Nq];
    #pragma unroll
    for (int n = 0; n < Nq; ++n) { pwr[n] = 1.f; pwi[n] = 0.f; }
    #pragma unroll
    for (int k = 0; k < 6; ++k) {
        const int s = 1 << k;
        const bool bit = (lam >> k) & 1;
        #pragma unroll
        for (int n = 0; n < Nq; ++n) {
            float mr = Ms[k][0][n], mi = Ms[k][1][n];
            float ur = __shfl_up(hr[n], s, 64);
            float ui = __shfl_up(hi_[n], s, 64);
            float vr = fmaf(mr, ur, fmaf(-mi, ui, hr[n]));
            float vi = fmaf(mr, ui, fmaf(mi, ur, hi_[n]));
            bool p = (lam >= s);
            hr[n]  = p ? vr : hr[n];
            hi_[n] = p ? vi : hi_[n];
            // square-and-multiply for pw (used by wave1's carry fold)
            float npr = pwr[n] * mr - pwi[n] * mi;
            float npi = pwr[n] * mi + pwi[n] * mr;
            pwr[n] = bit ? npr : pwr[n];
            pwi[n] = bit ? npi : pwi[n];
        }
    }

    // ---- wave0 publishes its total prefix T ----
    if (w == 0 && lam == 63) {
        #pragma unroll
        for (int n = 0; n < Nq; ++n) { Tbuf[0][n] = hr[n]; Tbuf[1][n] = hi_[n]; }
    }
    __syncthreads();

    // ---- exclusive carry: lam? P[lam-1] : 0, plus (wave1) pw * T ----
    #pragma unroll
    for (int n = 0; n < Nq; ++n) {
        float cr = __shfl_up(hr[n], 1, 64);
        float ci = __shfl_up(hi_[n], 1, 64);
        cr = lam ? cr : 0.f;
        ci = lam ? ci : 0.f;
        if (w == 1) {
            float tr = Tbuf[0][n], ti = Tbuf[1][n];
            cr = fmaf(pwr[n], tr, fmaf(-pwi[n], ti, cr));
            ci = fmaf(pwr[n], ti, fmaf(pwi[n], tr, ci));
        }
        hr[n] = cr; hi_[n] = ci;
    }

    // ---- pass C: re-run with carry, emit y to LDS ----
    float gpr[Nq], gpi[Nq];
    #pragma unroll
    for (int n = 0; n < Nq; ++n) { gpr[n] = cgr[n]; gpi[n] = cgi[n]; }
    const float om = omg[d];

    float* xcw = &xs[t * STR];
    for (int j = 0; j < 8; ++j) {
        float4 cur = *reinterpret_cast<const float4*>(xcw + 4 * j);
        float yo[4];
        #pragma unroll
        for (int u = 0; u < 4; ++u) {
            float xe = (u == 0) ? cur.x : (u == 1) ? cur.y : (u == 2) ? cur.z : cur.w;
            float f0 = om * xe, f1 = 0.f, f2 = 0.f, f3 = 0.f;
            #pragma unroll
            for (int n = 0; n < Nq; ++n) {
                float nr = fmaf(qrr[n], hr[n], fmaf(-qii[n], hi_[n], xe));
                float ni = fmaf(qrr[n], hi_[n], qii[n] * hr[n]);
                hr[n] = nr; hi_[n] = ni;
                if ((n & 3) == 0)      { f0 = fmaf(gpr[n], nr, f0); f0 = fmaf(-gpi[n], ni, f0); }
                else if ((n & 3) == 1) { f1 = fmaf(gpr[n], nr, f1); f1 = fmaf(-gpi[n], ni, f1); }
                else if ((n & 3) == 2) { f2 = fmaf(gpr[n], nr, f2); f2 = fmaf(-gpi[n], ni, f2); }
                else                   { f3 = fmaf(gpr[n], nr, f3); f3 = fmaf(-gpi[n], ni, f3); }
            }
            yo[u] = (f0 + f1) + (f2 + f3);
        }
        *reinterpret_cast<float4*>(xcw + 4 * j) = make_float4(yo[0], yo[1], yo[2], yo[3]);
    }
    __syncthreads();

    // ---- coalesced store ----
    #pragma unroll
    for (int i = 0; i < 8; ++i) {
        int e = i * 512 + t * 4;
        float4 v = *reinterpret_cast<const float4*>(&xs[(e >> 5) * STR + (e & 31)]);
        *reinterpret_cast<float4*>(yp + e) = v;
    }
}

extern "C" void kernel_launch(void* const* d_in, const int* in_sizes, int n_in,
                              void* d_out, int out_size, void* d_ws, size_t ws_size,
                              hipStream_t stream) {
    const float* x     = (const float*)d_in[0];
    const float* alpha = (const float*)d_in[1];
    const float* delta = (const float*)d_in[2];
    const float* theta = (const float*)d_in[3];
    const float* gmr   = (const float*)d_in[4];
    const float* gmi   = (const float*)d_in[5];
    const float* omg   = (const float*)d_in[6];

    dim3 grid(Bq * Dq);
    dim3 block(128);
    cema_kernel<<<grid, block, 0, stream>>>(x, alpha, delta, theta, gmr, gmi, omg,
                                            (float*)d_out);
}

// Round 14
// 129.739 us; speedup vs baseline: 3.0075x; 3.0075x over previous
//
#include <hip/hip_runtime.h>
#include <math.h>

// ComplexEMA: B=2, D=1024, N=16, L=4096.
// y[b,d,l] = Re( sum_n gp[d,n] * h[d,n,l] ) + omega[d]*x[b,d,l]
//   h[n,l] = q[n]*h[n,l-1] + x[l]
// v6: v5 structure with register pressure fixed.
//   - plain __launch_bounds__(128): v5's (128,4) forced VGPR=64 -> ~1GB
//     scratch spill traffic, 321us. Let the allocator pick (~115 expected).
//   - no pw[] arrays: wave1's (q^32)^lam * T0 via 6-step conditional ladder
//     applied to T0 AFTER the scan (Ms bits from LDS, zero persistent regs),
//     under a wave-uniform if(w==1).
//   - q reloaded from LDS per pass (dead across scan) to cut peak pressure.

#define Bq 2
#define Dq 1024
#define Nq 16
#define Lq 4096
#define STR 36   // chunk stride in floats: 144B, 16B-aligned; 36t%32==4t%32 -> no extra bank conflicts

__global__ __launch_bounds__(128) void cema_kernel(
    const float* __restrict__ x,
    const float* __restrict__ alpha,
    const float* __restrict__ delta,
    const float* __restrict__ theta,
    const float* __restrict__ gmr,
    const float* __restrict__ gmi,
    const float* __restrict__ omg,
    float* __restrict__ out)
{
    __shared__ float xs[128 * STR];        // 18432 B
    __shared__ float cqr[Nq], cqi[Nq], cgr[Nq], cgi[Nq];
    __shared__ float Ms[6][2][Nq];         // (q^32)^(2^k), k=0..5
    __shared__ float Tbuf[2][Nq];          // wave0 total prefix (lane 63)

    const int bd  = blockIdx.x;            // 0..2047
    const int d   = bd & (Dq - 1);
    const int t   = threadIdx.x;           // 0..127
    const int w   = t >> 6;                // wave id
    const int lam = t & 63;                // lane in wave

    const float* xp = x   + (size_t)bd * Lq;
    float*       yp = out + (size_t)bd * Lq;

    // ---- stage x into LDS, coalesced float4 ----
    #pragma unroll
    for (int i = 0; i < 8; ++i) {
        int e = i * 512 + t * 4;
        float4 v = *reinterpret_cast<const float4*>(xp + e);
        *reinterpret_cast<float4*>(&xs[(e >> 5) * STR + (e & 31)]) = v;
    }

    // ---- coefficients + q^32 ladder (threads 0..15) ----
    if (t < Nq) {
        const int n = t;
        float th  = theta[d];
        float f   = 1.f / (1.f + expf(-th));
        float phi = (float)(n + 1) * f * (float)(2.0 * M_PI / 16.0);
        float a   = 1.f / (1.f + expf(-alpha[d * Nq + n]));
        float dd  = 1.f / (1.f + expf(-delta[d * Nq + n]));
        float radius = fminf(1.f - a * dd, 1.f);
        float s, c;
        sincosf(phi, &s, &c);
        float qrv = radius * c, qiv = radius * s;
        cqr[n] = qrv; cqi[n] = qiv;
        cgr[n] = gmr[d * Nq + n] * 0.25f * a;   // scale = 1/sqrt(16)
        cgi[n] = gmi[d * Nq + n] * 0.25f * a;
        float mr = qrv, mi = qiv;               // q -> q^32 (5 squarings)
        #pragma unroll
        for (int k = 0; k < 5; ++k) { float t2 = mr*mr - mi*mi; mi = 2.f*mr*mi; mr = t2; }
        #pragma unroll
        for (int k = 0; k < 6; ++k) {           // ladder (q^32)^(2^k)
            Ms[k][0][n] = mr; Ms[k][1][n] = mi;
            float t2 = mr*mr - mi*mi; mi = 2.f*mr*mi; mr = t2;
        }
    }
    __syncthreads();

    float hr[Nq], hi_[Nq];
    #pragma unroll
    for (int n = 0; n < Nq; ++n) { hr[n] = 0.f; hi_[n] = 0.f; }

    // ---- pass A: local scan of own 32-elem chunk from LDS ----
    {
        float qrr[Nq], qii[Nq];
        #pragma unroll
        for (int n = 0; n < Nq; ++n) { qrr[n] = cqr[n]; qii[n] = cqi[n]; }
        const float4* xc4 = reinterpret_cast<const float4*>(&xs[t * STR]);
        for (int j = 0; j < 8; ++j) {
            float4 cur = xc4[j];
            #pragma unroll
            for (int u = 0; u < 4; ++u) {
                float xe = (u == 0) ? cur.x : (u == 1) ? cur.y : (u == 2) ? cur.z : cur.w;
                #pragma unroll
                for (int n = 0; n < Nq; ++n) {
                    float nr = fmaf(qrr[n], hr[n], fmaf(-qii[n], hi_[n], xe));
                    float ni = fmaf(qrr[n], hi_[n], qii[n] * hr[n]);
                    hr[n] = nr; hi_[n] = ni;
                }
            }
        }
    }

    // ---- in-wave KS scan (6 steps), multipliers from LDS ladder ----
    #pragma unroll
    for (int k = 0; k < 6; ++k) {
        const int s = 1 << k;
        #pragma unroll
        for (int n = 0; n < Nq; ++n) {
            float mr = Ms[k][0][n], mi = Ms[k][1][n];
            float ur = __shfl_up(hr[n], s, 64);
            float ui = __shfl_up(hi_[n], s, 64);
            float vr = fmaf(mr, ur, fmaf(-mi, ui, hr[n]));
            float vi = fmaf(mr, ui, fmaf(mi, ur, hi_[n]));
            bool p = (lam >= s);
            hr[n]  = p ? vr : hr[n];
            hi_[n] = p ? vi : hi_[n];
        }
    }

    // ---- wave0 publishes its total prefix T0 ----
    if (w == 0 && lam == 63) {
        #pragma unroll
        for (int n = 0; n < Nq; ++n) { Tbuf[0][n] = hr[n]; Tbuf[1][n] = hi_[n]; }
    }
    __syncthreads();

    // ---- exclusive carry: lam? P[lam-1] : 0 ----
    #pragma unroll
    for (int n = 0; n < Nq; ++n) {
        float cr = __shfl_up(hr[n], 1, 64);
        float ci = __shfl_up(hi_[n], 1, 64);
        hr[n]  = lam ? cr : 0.f;
        hi_[n] = lam ? ci : 0.f;
    }
    // ---- wave1: += (q^32)^lam * T0 via conditional ladder (no pw regs) ----
    if (w == 1) {
        #pragma unroll
        for (int n = 0; n < Nq; ++n) {
            float tr = Tbuf[0][n], ti = Tbuf[1][n];
            #pragma unroll
            for (int k = 0; k < 6; ++k) {
                float mr = Ms[k][0][n], mi = Ms[k][1][n];
                float ntr = tr * mr - ti * mi;
                float nti = tr * mi + ti * mr;
                bool bit = (lam >> k) & 1;
                tr = bit ? ntr : tr;
                ti = bit ? nti : ti;
            }
            hr[n]  += tr;
            hi_[n] += ti;
        }
    }

    // ---- pass C: re-run with carry, emit y to LDS ----
    {
        float qrr[Nq], qii[Nq], gpr[Nq], gpi[Nq];
        #pragma unroll
        for (int n = 0; n < Nq; ++n) {
            qrr[n] = cqr[n]; qii[n] = cqi[n];
            gpr[n] = cgr[n]; gpi[n] = cgi[n];
        }
        const float om = omg[d];

        float* xcw = &xs[t * STR];
        for (int j = 0; j < 8; ++j) {
            float4 cur = *reinterpret_cast<const float4*>(xcw + 4 * j);
            float yo[4];
            #pragma unroll
            for (int u = 0; u < 4; ++u) {
                float xe = (u == 0) ? cur.x : (u == 1) ? cur.y : (u == 2) ? cur.z : cur.w;
                float f0 = om * xe, f1 = 0.f, f2 = 0.f, f3 = 0.f;
                #pragma unroll
                for (int n = 0; n < Nq; ++n) {
                    float nr = fmaf(qrr[n], hr[n], fmaf(-qii[n], hi_[n], xe));
                    float ni = fmaf(qrr[n], hi_[n], qii[n] * hr[n]);
                    hr[n] = nr; hi_[n] = ni;
                    if ((n & 3) == 0)      { f0 = fmaf(gpr[n], nr, f0); f0 = fmaf(-gpi[n], ni, f0); }
                    else if ((n & 3) == 1) { f1 = fmaf(gpr[n], nr, f1); f1 = fmaf(-gpi[n], ni, f1); }
                    else if ((n & 3) == 2) { f2 = fmaf(gpr[n], nr, f2); f2 = fmaf(-gpi[n], ni, f2); }
                    else                   { f3 = fmaf(gpr[n], nr, f3); f3 = fmaf(-gpi[n], ni, f3); }
                }
                yo[u] = (f0 + f1) + (f2 + f3);
            }
            *reinterpret_cast<float4*>(xcw + 4 * j) = make_float4(yo[0], yo[1], yo[2], yo[3]);
        }
    }
    __syncthreads();

    // ---- coalesced store ----
    #pragma unroll
    for (int i = 0; i < 8; ++i) {
        int e = i * 512 + t * 4;
        float4 v = *reinterpret_cast<const float4*>(&xs[(e >> 5) * STR + (e & 31)]);
        *reinterpret_cast<float4*>(yp + e) = v;
    }
}

extern "C" void kernel_launch(void* const* d_in, const int* in_sizes, int n_in,
                              void* d_out, int out_size, void* d_ws, size_t ws_size,
                              hipStream_t stream) {
    const float* x     = (const float*)d_in[0];
    const float* alpha = (const float*)d_in[1];
    const float* delta = (const float*)d_in[2];
    const float* theta = (const float*)d_in[3];
    const float* gmr   = (const float*)d_in[4];
    const float* gmi   = (const float*)d_in[5];
    const float* omg   = (const float*)d_in[6];

    dim3 grid(Bq * Dq);
    dim3 block(128);
    cema_kernel<<<grid, block, 0, stream>>>(x, alpha, delta, theta, gmr, gmi, omg,
                                            (float*)d_out);
}